// Round 5
// baseline (51.071 us; speedup 1.0000x reference)
//
#include <hip/hip_runtime.h>
#include <math.h>

#define FFT_N   4096
#define NT      512
// Padded LDS index: +1 float2 per 16 keeps strided stage accesses at/near the
// wave64 b64 floor. (i+512r)>>4 = (i>>4)+32r, so per-thread stage offsets fold
// to base + 544r -> ds_read/write immediate offsets.
#define PHYS(i) ((i) + ((i) >> 4))
#define LDS_SZ  (FFT_N + FFT_N / 16)

__device__ __forceinline__ float2 cadd(float2 a, float2 b) { return make_float2(a.x + b.x, a.y + b.y); }
__device__ __forceinline__ float2 csub(float2 a, float2 b) { return make_float2(a.x - b.x, a.y - b.y); }
__device__ __forceinline__ float2 cmul(float2 a, float2 b) { return make_float2(a.x * b.x - a.y * b.y, a.x * b.y + a.y * b.x); }

// In-place 4-point DFT (w4 = -i), outputs in natural order.
__device__ __forceinline__ void dft4(float2& a, float2& b, float2& c, float2& d) {
    float2 t0 = cadd(a, c);
    float2 t1 = csub(a, c);
    float2 t2 = cadd(b, d);
    float2 t3 = make_float2(b.y - d.y, d.x - b.x);  // -i*(b-d)
    a = cadd(t0, t2);
    b = cadd(t1, t3);
    c = csub(t0, t2);
    d = csub(t1, t3);
}

// 8-point DFT, natural-order in/out (DIT: evens/odds DFT4 + combine).
__device__ __forceinline__ void dft8(float2 v[8]) {
    const float R2 = 0.70710678118654752440f;
    float2 e0 = v[0], e1 = v[2], e2 = v[4], e3 = v[6];
    float2 o0 = v[1], o1 = v[3], o2 = v[5], o3 = v[7];
    dft4(e0, e1, e2, e3);
    dft4(o0, o1, o2, o3);
    // odd twiddles: w8^1=(r2,-r2), w8^2=-i, w8^3=(-r2,-r2)
    o1 = make_float2(R2 * (o1.x + o1.y), R2 * (o1.y - o1.x));
    o2 = make_float2(o2.y, -o2.x);
    o3 = make_float2(R2 * (o3.y - o3.x), -R2 * (o3.x + o3.y));
    v[0] = cadd(e0, o0); v[4] = csub(e0, o0);
    v[1] = cadd(e1, o1); v[5] = csub(e1, o1);
    v[2] = cadd(e2, o2); v[6] = csub(e2, o2);
    v[3] = cadd(e3, o3); v[7] = csub(e3, o3);
}

__device__ __forceinline__ void load8(const float2* buf, int t, float2 v[8]) {
    #pragma unroll
    for (int r = 0; r < 8; ++r) v[r] = buf[PHYS(t + 512 * r)];
}

// Radix-8 Stockham stage store; inter-stage twiddles w_q = exp(-2*pi*i*j*M*q/N)
// built log-depth from one sincos (w2=w1^2, w4=w2^2, ...).
template <int M, bool TW>
__device__ __forceinline__ void store_stage8(float2* buf, int t, float2 v[8]) {
    const int j = t / M;
    const int k = t % M;
    const int obase = j * 8 * M + k;
    if (TW) {
        float sn, cs;
        __sincosf((float)j * (-6.28318530717958647692f * (float)M / (float)FFT_N), &sn, &cs);
        const float2 w1 = make_float2(cs, sn);
        const float2 w2 = cmul(w1, w1);
        const float2 w3 = cmul(w2, w1);
        const float2 w4 = cmul(w2, w2);
        buf[PHYS(obase)]         = v[0];
        buf[PHYS(obase + 1 * M)] = cmul(v[1], w1);
        buf[PHYS(obase + 2 * M)] = cmul(v[2], w2);
        buf[PHYS(obase + 3 * M)] = cmul(v[3], w3);
        buf[PHYS(obase + 4 * M)] = cmul(v[4], w4);
        buf[PHYS(obase + 5 * M)] = cmul(v[5], cmul(w4, w1));
        buf[PHYS(obase + 6 * M)] = cmul(v[6], cmul(w4, w2));
        buf[PHYS(obase + 7 * M)] = cmul(v[7], cmul(w4, w3));
    } else {
        #pragma unroll
        for (int q = 0; q < 8; ++q)
            buf[PHYS(obase + q * M)] = v[q];
    }
}

// One 512-thread block per PAIR of windows: z = x1 + i*x2, one 4096-pt complex
// FFT as 4 radix-8 Stockham stages (8 pts/thread), unpack |F1|^2,|F2|^2 via
// conjugate symmetry. 34 KB LDS shared by 8 waves -> 4 blocks/CU = 32 waves/CU.
__global__ __launch_bounds__(NT, 8) void spec_fft_kernel(const float* __restrict__ x,
                                                         float* __restrict__ out) {
    __shared__ float2 buf[LDS_SZ];
    const int t = threadIdx.x;
    const size_t base = (size_t)blockIdx.x * (2 * FFT_N);
    const float* __restrict__ x1 = x + base + t;
    const float* __restrict__ x2 = x + base + FFT_N + t;

    float2 v[8];
    #pragma unroll
    for (int r = 0; r < 8; ++r)
        v[r] = make_float2(x1[512 * r], x2[512 * r]);

    // Stage 1 (M=1)
    dft8(v);
    store_stage8<1, true>(buf, t, v);
    __syncthreads();

    // Stage 2 (M=8)
    load8(buf, t, v);
    __syncthreads();
    dft8(v);
    store_stage8<8, true>(buf, t, v);
    __syncthreads();

    // Stage 3 (M=64)
    load8(buf, t, v);
    __syncthreads();
    dft8(v);
    store_stage8<64, true>(buf, t, v);
    __syncthreads();

    // Stage 4 (M=512): j==0 -> no twiddles; thread t ends holding Z[t+512q]
    // in v[q] (natural order). Store to LDS only for the conjugate mirrors.
    load8(buf, t, v);
    __syncthreads();
    dft8(v);
    #pragma unroll
    for (int q = 0; q < 8; ++q)
        buf[PHYS(t + 512 * q)] = v[q];
    __syncthreads();

    // Fused epilogue: F1(k)=(Z(k)+conj(Z(N-k)))/2, F2(k)=(Z(k)-conj(Z(N-k)))/(2i)
    float* __restrict__ o1 = out + base;
    float* __restrict__ o2 = out + base + FFT_N;
    #pragma unroll
    for (int q = 0; q < 8; ++q) {
        const int k = t + 512 * q;
        float2 zk = v[q];
        float2 zn = buf[PHYS((FFT_N - k) & (FFT_N - 1))];
        float e1r = zk.x + zn.x, e1i = zk.y - zn.y;   // 2*F1
        float e2r = zk.x - zn.x, e2i = zk.y + zn.y;   // 2i*F2 (same magnitude)
        __builtin_nontemporal_store(0.25f * (e1r * e1r + e1i * e1i), o1 + k);
        __builtin_nontemporal_store(0.25f * (e2r * e2r + e2i * e2i), o2 + k);
    }
}

extern "C" void kernel_launch(void* const* d_in, const int* in_sizes, int n_in,
                              void* d_out, int out_size, void* d_ws, size_t ws_size,
                              hipStream_t stream) {
    const float* x = (const float*)d_in[0];
    float* out = (float*)d_out;
    const int B = in_sizes[0] / FFT_N;  // 8192
    spec_fft_kernel<<<B / 2, NT, 0, stream>>>(x, out);
}

// Round 6
// 49.354 us; speedup vs baseline: 1.0348x; 1.0348x over previous
//
#include <hip/hip_runtime.h>
#include <math.h>

#define FFT_N   4096
#define NT      256
// Padded LDS index: +1 float2 per 16 keeps every stage's strided access at
// the wave64 b64 floor (even bank-pair coverage, no above-floor conflicts).
#define PHYS(i) ((i) + ((i) >> 4))
#define LDS_SZ  (FFT_N + FFT_N / 16)

// ext_vector float2 so clang lowers complex arithmetic to packed-fp32
// (v_pk_add_f32 / v_pk_fma_f32 with op_sel splat/swizzle + neg modifiers).
typedef float f2 __attribute__((ext_vector_type(2)));

// cmul as splat/swizzle form: v_pk_mul + v_pk_fma (2 insts vs 4 scalar).
__device__ __forceinline__ f2 cmul(f2 a, f2 b) {
    return (f2){a.x, a.x} * b + (f2){-a.y, a.y} * (f2){b.y, b.x};
}

// In-place 4-point DFT (w4 = -i); adds/subs are single pk ops.
__device__ __forceinline__ void dft4(f2& a, f2& b, f2& c, f2& d) {
    f2 t0 = a + c;
    f2 t1 = a - c;
    f2 t2 = b + d;
    f2 s  = b - d;
    f2 t3 = (f2){s.y, -s.x};  // -i*(b-d)
    a = t0 + t2;
    b = t1 + t3;
    c = t0 - t2;
    d = t1 - t3;
}

// 16-point DFT in registers via radix-4 x radix-4.
// Input v[r] = c_r. Output DFT16[q1 + 4*q2] lands in v[4*q1 + q2]
// (caller maps q -> reg = ((q&3)<<2)|(q>>2)).
__device__ __forceinline__ void dft16(f2 v[16]) {
    #pragma unroll
    for (int r1 = 0; r1 < 4; ++r1)
        dft4(v[r1], v[r1 + 4], v[r1 + 8], v[r1 + 12]);

    const float C1 = 0.92387953251128675613f;  // cos(pi/8)
    const float S1 = 0.38268343236508977173f;  // sin(pi/8)
    const float R2 = 0.70710678118654752440f;  // sqrt(2)/2
    v[5]  = cmul(v[5],  (f2){ C1, -S1});   // w16^1
    v[9]  = cmul(v[9],  (f2){ R2, -R2});   // w16^2
    v[13] = cmul(v[13], (f2){ S1, -C1});   // w16^3
    v[6]  = cmul(v[6],  (f2){ R2, -R2});   // w16^2
    v[10] = (f2){v[10].y, -v[10].x};       // w16^4 = -i
    v[14] = cmul(v[14], (f2){-R2, -R2});   // w16^6
    v[7]  = cmul(v[7],  (f2){ S1, -C1});   // w16^3
    v[11] = cmul(v[11], (f2){-R2, -R2});   // w16^6
    v[15] = cmul(v[15], (f2){-C1,  S1});   // w16^9
    #pragma unroll
    for (int q1 = 0; q1 < 4; ++q1)
        dft4(v[4 * q1], v[4 * q1 + 1], v[4 * q1 + 2], v[4 * q1 + 3]);
}

// Stage store with inter-stage twiddles built log-depth (dep chain ~4 deep).
template <int M>
__device__ __forceinline__ void store_stage_tw(f2* buf, int tid, f2 v[16]) {
    const int j = tid / M;
    const int k = tid % M;
    const int obase = j * 16 * M + k;
    float sn, cs;
    __sincosf((float)j * (-6.28318530717958647692f * (float)M / (float)FFT_N), &sn, &cs);
    f2 w[16];
    w[1]  = (f2){cs, sn};
    w[2]  = cmul(w[1], w[1]);
    w[3]  = cmul(w[2], w[1]);
    w[4]  = cmul(w[2], w[2]);
    w[5]  = cmul(w[4], w[1]);
    w[6]  = cmul(w[4], w[2]);
    w[7]  = cmul(w[4], w[3]);
    w[8]  = cmul(w[4], w[4]);
    w[9]  = cmul(w[8], w[1]);
    w[10] = cmul(w[8], w[2]);
    w[11] = cmul(w[8], w[3]);
    w[12] = cmul(w[8], w[4]);
    w[13] = cmul(w[8], w[5]);
    w[14] = cmul(w[8], w[6]);
    w[15] = cmul(w[8], w[7]);
    buf[PHYS(obase)] = v[0];
    #pragma unroll
    for (int q = 1; q < 16; ++q) {
        const int reg = ((q & 3) << 2) | (q >> 2);
        buf[PHYS(obase + q * M)] = cmul(v[reg], w[q]);
    }
}

__device__ __forceinline__ void load_stage(const f2* buf, int tid, f2 v[16]) {
    #pragma unroll
    for (int r = 0; r < 16; ++r) v[r] = buf[PHYS(tid + 256 * r)];
}

// One block per PAIR of windows: z = x1 + i*x2, one 4096-pt complex FFT,
// unpack |F1|^2, |F2|^2 via conjugate symmetry. Because x1,x2 are real, the
// power spectra are symmetric (out[N-k] == out[k]) -> compute only k<2048 and
// store each value to both k and N-k (mirror stores are reverse-contiguous,
// still coalesced). Stage-3 LDS store keeps only the halves needed as mirrors.
__global__ __launch_bounds__(NT) void spec_fft_kernel(const float* __restrict__ x,
                                                      float* __restrict__ out) {
    __shared__ f2 buf[LDS_SZ];
    const int t = threadIdx.x;
    const size_t base = (size_t)blockIdx.x * (2 * FFT_N);
    const float* __restrict__ x1 = x + base + t;
    const float* __restrict__ x2 = x + base + FFT_N + t;

    f2 v[16];
    #pragma unroll
    for (int r = 0; r < 16; ++r)
        v[r] = (f2){x1[256 * r], x2[256 * r]};

    // Stage 1 (M=1)
    dft16(v);
    store_stage_tw<1>(buf, t, v);
    __syncthreads();

    // Stage 2 (M=16)
    load_stage(buf, t, v);
    __syncthreads();
    dft16(v);
    store_stage_tw<16>(buf, t, v);
    __syncthreads();

    // Stage 3 (M=256): j==0 -> no twiddles. Thread t ends holding Z[t+256q]
    // in v[reg(q)]. Only q=0 and q>=8 are ever read back as mirrors.
    load_stage(buf, t, v);
    __syncthreads();
    dft16(v);
    buf[PHYS(t)] = v[0];  // reg(0)=0; needed as mirror of k=t (q=0 outputs)
    #pragma unroll
    for (int q = 8; q < 16; ++q) {
        const int reg = ((q & 3) << 2) | (q >> 2);
        buf[PHYS(t + 256 * q)] = v[reg];
    }
    __syncthreads();

    // Fused symmetric epilogue over k = t + 256q, q < 8 (k in [0, 2048)):
    // F1(k) = (Z(k)+conj(Z(N-k)))/2, F2(k) = (Z(k)-conj(Z(N-k)))/(2i)
    float* __restrict__ o1 = out + base;
    float* __restrict__ o2 = out + base + FFT_N;
    #pragma unroll
    for (int q = 0; q < 8; ++q) {
        const int reg = ((q & 3) << 2) | (q >> 2);
        const int k = t + 256 * q;
        const int m = (FFT_N - k) & (FFT_N - 1);
        f2 zk = v[reg];
        f2 zn = buf[PHYS(m)];
        f2 zc = (f2){zn.x, -zn.y};       // conj(Z(N-k))
        f2 e1 = zk + zc;                  // 2*F1
        f2 e2 = zk - zc;                  // 2i*F2 (same magnitude as 2*F2)
        float p1 = 0.25f * (e1.x * e1.x + e1.y * e1.y);
        float p2 = 0.25f * (e2.x * e2.x + e2.y * e2.y);
        __builtin_nontemporal_store(p1, o1 + k);
        __builtin_nontemporal_store(p2, o2 + k);
        __builtin_nontemporal_store(p1, o1 + m);  // k=0: same addr, same value
        __builtin_nontemporal_store(p2, o2 + m);
    }
    if (t == 0) {  // k = 2048 self-mirror: F1 = Re(Z), F2 = Im(Z)
        f2 z = buf[PHYS(2048)];
        __builtin_nontemporal_store(z.x * z.x, o1 + 2048);
        __builtin_nontemporal_store(z.y * z.y, o2 + 2048);
    }
}

extern "C" void kernel_launch(void* const* d_in, const int* in_sizes, int n_in,
                              void* d_out, int out_size, void* d_ws, size_t ws_size,
                              hipStream_t stream) {
    const float* x = (const float*)d_in[0];
    float* out = (float*)d_out;
    const int B = in_sizes[0] / FFT_N;  // 8192
    spec_fft_kernel<<<B / 2, NT, 0, stream>>>(x, out);
}

// Round 7
// 46.705 us; speedup vs baseline: 1.0935x; 1.0567x over previous
//
#include <hip/hip_runtime.h>
#include <math.h>

#define FFT_N   4096
#define NT      256
// Padded LDS index: +1 float2 per 16 keeps every stage's strided access at
// the wave64 b64 floor (even bank-pair coverage, no above-floor conflicts).
#define PHYS(i) ((i) + ((i) >> 4))
#define LDS_SZ  (FFT_N + FFT_N / 16)

// ext_vector float2 so clang lowers complex arithmetic to packed-fp32
// (v_pk_add_f32 / v_pk_fma_f32 with op_sel splat/swizzle + neg modifiers).
typedef float f2 __attribute__((ext_vector_type(2)));

// cmul as splat/swizzle form: v_pk_mul + v_pk_fma (2 insts vs 4 scalar).
__device__ __forceinline__ f2 cmul(f2 a, f2 b) {
    return (f2){a.x, a.x} * b + (f2){-a.y, a.y} * (f2){b.y, b.x};
}

// In-place 4-point DFT (w4 = -i); adds/subs are single pk ops.
__device__ __forceinline__ void dft4(f2& a, f2& b, f2& c, f2& d) {
    f2 t0 = a + c;
    f2 t1 = a - c;
    f2 t2 = b + d;
    f2 s  = b - d;
    f2 t3 = (f2){s.y, -s.x};  // -i*(b-d)
    a = t0 + t2;
    b = t1 + t3;
    c = t0 - t2;
    d = t1 - t3;
}

// 16-point DFT in registers via radix-4 x radix-4.
// Input v[r] = c_r. Output DFT16[q1 + 4*q2] lands in v[4*q1 + q2]
// (caller maps q -> reg = ((q&3)<<2)|(q>>2)).
__device__ __forceinline__ void dft16(f2 v[16]) {
    #pragma unroll
    for (int r1 = 0; r1 < 4; ++r1)
        dft4(v[r1], v[r1 + 4], v[r1 + 8], v[r1 + 12]);

    const float C1 = 0.92387953251128675613f;  // cos(pi/8)
    const float S1 = 0.38268343236508977173f;  // sin(pi/8)
    const float R2 = 0.70710678118654752440f;  // sqrt(2)/2
    v[5]  = cmul(v[5],  (f2){ C1, -S1});   // w16^1
    v[9]  = cmul(v[9],  (f2){ R2, -R2});   // w16^2
    v[13] = cmul(v[13], (f2){ S1, -C1});   // w16^3
    v[6]  = cmul(v[6],  (f2){ R2, -R2});   // w16^2
    v[10] = (f2){v[10].y, -v[10].x};       // w16^4 = -i
    v[14] = cmul(v[14], (f2){-R2, -R2});   // w16^6
    v[7]  = cmul(v[7],  (f2){ S1, -C1});   // w16^3
    v[11] = cmul(v[11], (f2){-R2, -R2});   // w16^6
    v[15] = cmul(v[15], (f2){-C1,  S1});   // w16^9
    #pragma unroll
    for (int q1 = 0; q1 < 4; ++q1)
        dft4(v[4 * q1], v[4 * q1 + 1], v[4 * q1 + 2], v[4 * q1 + 3]);
}

// Stage store with inter-stage twiddles built log-depth (dep chain ~4 deep).
template <int M>
__device__ __forceinline__ void store_stage_tw(f2* buf, int tid, f2 v[16]) {
    const int j = tid / M;
    const int k = tid % M;
    const int obase = j * 16 * M + k;
    float sn, cs;
    __sincosf((float)j * (-6.28318530717958647692f * (float)M / (float)FFT_N), &sn, &cs);
    f2 w[16];
    w[1]  = (f2){cs, sn};
    w[2]  = cmul(w[1], w[1]);
    w[3]  = cmul(w[2], w[1]);
    w[4]  = cmul(w[2], w[2]);
    w[5]  = cmul(w[4], w[1]);
    w[6]  = cmul(w[4], w[2]);
    w[7]  = cmul(w[4], w[3]);
    w[8]  = cmul(w[4], w[4]);
    w[9]  = cmul(w[8], w[1]);
    w[10] = cmul(w[8], w[2]);
    w[11] = cmul(w[8], w[3]);
    w[12] = cmul(w[8], w[4]);
    w[13] = cmul(w[8], w[5]);
    w[14] = cmul(w[8], w[6]);
    w[15] = cmul(w[8], w[7]);
    buf[PHYS(obase)] = v[0];
    #pragma unroll
    for (int q = 1; q < 16; ++q) {
        const int reg = ((q & 3) << 2) | (q >> 2);
        buf[PHYS(obase + q * M)] = cmul(v[reg], w[q]);
    }
}

__device__ __forceinline__ void load_stage(const f2* buf, int tid, f2 v[16]) {
    #pragma unroll
    for (int r = 0; r < 16; ++r) v[r] = buf[PHYS(tid + 256 * r)];
}

// One block per PAIR of windows: z = x1 + i*x2, one 4096-pt complex FFT,
// unpack |F1|^2, |F2|^2 via conjugate symmetry. Power spectra of real inputs
// are symmetric (out[N-k] == out[k]) -> compute k<2048, store both halves.
// ROUND 7 A/B: plain stores instead of nontemporal (write stream through the
// normal L2 write-back path, which fillBuffer drives at 6.9 TB/s).
__global__ __launch_bounds__(NT) void spec_fft_kernel(const float* __restrict__ x,
                                                      float* __restrict__ out) {
    __shared__ f2 buf[LDS_SZ];
    const int t = threadIdx.x;
    const size_t base = (size_t)blockIdx.x * (2 * FFT_N);
    const float* __restrict__ x1 = x + base + t;
    const float* __restrict__ x2 = x + base + FFT_N + t;

    f2 v[16];
    #pragma unroll
    for (int r = 0; r < 16; ++r)
        v[r] = (f2){x1[256 * r], x2[256 * r]};

    // Stage 1 (M=1)
    dft16(v);
    store_stage_tw<1>(buf, t, v);
    __syncthreads();

    // Stage 2 (M=16)
    load_stage(buf, t, v);
    __syncthreads();
    dft16(v);
    store_stage_tw<16>(buf, t, v);
    __syncthreads();

    // Stage 3 (M=256): j==0 -> no twiddles. Thread t ends holding Z[t+256q]
    // in v[reg(q)]. Only q=0 and q>=8 are ever read back as mirrors.
    load_stage(buf, t, v);
    __syncthreads();
    dft16(v);
    buf[PHYS(t)] = v[0];  // reg(0)=0; needed as mirror of k=t (q=0 outputs)
    #pragma unroll
    for (int q = 8; q < 16; ++q) {
        const int reg = ((q & 3) << 2) | (q >> 2);
        buf[PHYS(t + 256 * q)] = v[reg];
    }
    __syncthreads();

    // Fused symmetric epilogue over k = t + 256q, q < 8 (k in [0, 2048)):
    // F1(k) = (Z(k)+conj(Z(N-k)))/2, F2(k) = (Z(k)-conj(Z(N-k)))/(2i)
    float* __restrict__ o1 = out + base;
    float* __restrict__ o2 = out + base + FFT_N;
    #pragma unroll
    for (int q = 0; q < 8; ++q) {
        const int reg = ((q & 3) << 2) | (q >> 2);
        const int k = t + 256 * q;
        const int m = (FFT_N - k) & (FFT_N - 1);
        f2 zk = v[reg];
        f2 zn = buf[PHYS(m)];
        f2 zc = (f2){zn.x, -zn.y};       // conj(Z(N-k))
        f2 e1 = zk + zc;                  // 2*F1
        f2 e2 = zk - zc;                  // 2i*F2 (same magnitude as 2*F2)
        float p1 = 0.25f * (e1.x * e1.x + e1.y * e1.y);
        float p2 = 0.25f * (e2.x * e2.x + e2.y * e2.y);
        o1[k] = p1;
        o2[k] = p2;
        o1[m] = p1;  // k=0: same addr, same value
        o2[m] = p2;
    }
    if (t == 0) {  // k = 2048 self-mirror: F1 = Re(Z), F2 = Im(Z)
        f2 z = buf[PHYS(2048)];
        o1[2048] = z.x * z.x;
        o2[2048] = z.y * z.y;
    }
}

extern "C" void kernel_launch(void* const* d_in, const int* in_sizes, int n_in,
                              void* d_out, int out_size, void* d_ws, size_t ws_size,
                              hipStream_t stream) {
    const float* x = (const float*)d_in[0];
    float* out = (float*)d_out;
    const int B = in_sizes[0] / FFT_N;  // 8192
    spec_fft_kernel<<<B / 2, NT, 0, stream>>>(x, out);
}